// Round 11
// baseline (337.192 us; speedup 1.0000x reference)
//
#include <hip/hip_runtime.h>

#define B_SZ 2
#define C_IN 384
#define N_TOK 2048
#define HEADS 8
#define DH 48
#define J3 1152
// ATTN_SCALE * log2(e): S is computed in log2 domain (v_exp_f32 is 2^x)
#define QSCALE_LOG2 0.20823509110768f
#define KSPLIT 4
#define KEYS_PER_SPLIT 512               // N_TOK / KSPLIT
#define DEFER_THR 11.0f                  // P bounded by 2^11 = 2048 (fp16-safe)

typedef __attribute__((ext_vector_type(8))) _Float16 f16x8;
typedef __attribute__((ext_vector_type(4))) _Float16 f16x4;
typedef __attribute__((ext_vector_type(4))) float f32x4;

__device__ __forceinline__ unsigned short f2h(float f) {
  _Float16 h = (_Float16)f;
  return __builtin_bit_cast(unsigned short, h);
}
__device__ __forceinline__ uint pk2(float a, float b) {
  return __builtin_bit_cast(uint, __builtin_amdgcn_cvt_pkrtz(a, b));
}
__device__ __forceinline__ float exp2g(float x) {
  return __builtin_amdgcn_exp2f(x);
}

// ---------------- kernel 0: fused transpose+convert prep -------------------
// Also zeroes the split-k counters each launch (graph-replay safe).
__global__ __launch_bounds__(256) void tr_kernel(
    const float* __restrict__ x, const float* __restrict__ wq,
    const float* __restrict__ wo, unsigned short* __restrict__ xh,
    unsigned short* __restrict__ wqh, unsigned short* __restrict__ woh,
    int* __restrict__ ctr) {
  const int tid = threadIdx.x;
  if (blockIdx.x == 0 && blockIdx.y == 0 && blockIdx.z == 0) {
    if (tid < 256) ctr[tid] = 0;   // 16 qt x 16 bh counters
  }
  const int z = blockIdx.z;
  const float* src;
  unsigned short* dst;
  int C;
  if (z < 2) {
    src = x + (size_t)z * C_IN * N_TOK;
    dst = xh + (size_t)z * N_TOK * C_IN;
    C = N_TOK;
  } else if (z == 2) {
    src = wq; dst = wqh; C = J3;
  } else {
    src = wo; dst = woh; C = C_IN;
  }
  const int c0 = blockIdx.x * 64;
  const int r0 = blockIdx.y * 64;
  if (c0 >= C) return;
  __shared__ unsigned short T[64][74];
  const int cc = tid & 63;
#pragma unroll
  for (int i = 0; i < 16; ++i) {
    const int rr = 4 * i + (tid >> 6);
    T[cc][rr] = f2h(src[(size_t)(r0 + rr) * C + c0 + cc]);
  }
  __syncthreads();
  const int cc2 = tid >> 2;
  const int seg = (tid & 3) * 16;
  uint v[8];
#pragma unroll
  for (int k = 0; k < 8; ++k)
    v[k] = (uint)T[cc2][seg + 2 * k] | ((uint)T[cc2][seg + 2 * k + 1] << 16);
  unsigned short* dp = dst + (size_t)(c0 + cc2) * C_IN + r0 + seg;
  *(uint4*)dp = make_uint4(v[0], v[1], v[2], v[3]);
  *(uint4*)(dp + 8) = make_uint4(v[4], v[5], v[6], v[7]);
}

// ---------------- kernel 1: QKV GEMM via fp16 MFMA -------------------------
// V-blocks (j0 >= 768) transpose their output through LDS so Vo rows store
// n-contiguous (the direct path was a 64-line scatter per store inst).
__global__ __launch_bounds__(256) void qkv_mfma(
    const unsigned short* __restrict__ xh, const unsigned short* __restrict__ wqh,
    unsigned short* __restrict__ Qo, unsigned short* __restrict__ Ko,
    unsigned short* __restrict__ Vo) {
  __shared__ __align__(16) unsigned short Ts[128][72];
  __shared__ __align__(16) unsigned short Ws[64][72];
  const int tid = threadIdx.x;
  const int w = tid >> 6, lane = tid & 63;
  const int lc = lane & 15, lg = lane >> 4;
  const int m0 = blockIdx.x * 128;
  const int j0 = blockIdx.y * 64;
  const int b = m0 >> 11;

  f32x4 acc[2][4];
#pragma unroll
  for (int i = 0; i < 2; ++i)
#pragma unroll
    for (int j = 0; j < 4; ++j) acc[i][j] = (f32x4){0.f, 0.f, 0.f, 0.f};

  const int trow = tid & 127, tseg = tid >> 7;
  const int wrow = tid & 63,  wseg = tid >> 6;

  for (int kk = 0; kk < C_IN; kk += 64) {
    {
      const uint4* s = (const uint4*)(xh + (size_t)(m0 + trow) * C_IN + kk + tseg * 32);
      uint4* d = (uint4*)&Ts[trow][tseg * 32];
      d[0] = s[0]; d[1] = s[1]; d[2] = s[2]; d[3] = s[3];
      const uint4* s2 = (const uint4*)(wqh + (size_t)(j0 + wrow) * C_IN + kk + wseg * 16);
      uint4* d2 = (uint4*)&Ws[wrow][wseg * 16];
      d2[0] = s2[0]; d2[1] = s2[1];
    }
    __syncthreads();
    f16x8 a[2][2], bf[4][2];
#pragma unroll
    for (int mt = 0; mt < 2; ++mt)
#pragma unroll
      for (int kh = 0; kh < 2; ++kh)
        a[mt][kh] = *(const f16x8*)&Ts[32 * w + 16 * mt + lc][32 * kh + 8 * lg];
#pragma unroll
    for (int jt = 0; jt < 4; ++jt)
#pragma unroll
      for (int kh = 0; kh < 2; ++kh)
        bf[jt][kh] = *(const f16x8*)&Ws[16 * jt + lc][32 * kh + 8 * lg];
#pragma unroll
    for (int mt = 0; mt < 2; ++mt)
#pragma unroll
      for (int jt = 0; jt < 4; ++jt)
#pragma unroll
        for (int kh = 0; kh < 2; ++kh)
          acc[mt][jt] = __builtin_amdgcn_mfma_f32_16x16x32_f16(a[mt][kh], bf[jt][kh], acc[mt][jt], 0, 0, 0);
    __syncthreads();
  }

  if (j0 >= 768) {
    // -------- V path: LDS transpose then coalesced row stores --------
    unsigned short* Tv = &Ts[0][0];   // viewed as [64 j][136 m]
#pragma unroll
    for (int jt = 0; jt < 4; ++jt)
#pragma unroll
      for (int mt = 0; mt < 2; ++mt)
#pragma unroll
        for (int r = 0; r < 4; ++r)
          Tv[(16 * jt + lc) * 136 + (32 * w + 16 * mt + 4 * lg + r)] =
              f2h(acc[mt][jt][r]);
    __syncthreads();
    const int n0 = m0 & 2047;
#pragma unroll
    for (int i = 0; i < 4; ++i) {
      const int s = tid + i * 256;
      const int row = s >> 4;
      const int segoff = (s & 15) * 8;
      const int rr2 = j0 - 768 + row;
      const int head = rr2 / DH;
      const int d = rr2 - head * DH;
      const int bh = b * HEADS + head;
      *(uint4*)(Vo + ((size_t)bh * DH + d) * N_TOK + n0 + segoff) =
          *(const uint4*)&Tv[row * 136 + segoff];
    }
  } else {
    // -------- Q/K path: direct stores --------
#pragma unroll
    for (int jt = 0; jt < 4; ++jt) {
      const int jlo = j0 + 16 * jt;
      const int which = jlo / 384;
      const int rr = jlo - which * 384;
      const int head = rr / DH;
      const int dbase = rr - head * DH;
      const int d = dbase + lc;
      const int bh = b * HEADS + head;
#pragma unroll
      for (int mt = 0; mt < 2; ++mt)
#pragma unroll
        for (int r = 0; r < 4; ++r) {
          const int n = (m0 + 32 * w + 16 * mt + 4 * lg + r) & 2047;
          float val = fminf(fmaxf(acc[mt][jt][r], -5.f), 5.f);
          if (which == 0) {
            Qo[((size_t)bh * N_TOK + n) * DH + d] = f2h(val * QSCALE_LOG2);
          } else {
            Ko[((size_t)bh * N_TOK + n) * DH + d] = f2h(val);
          }
        }
    }
  }
}

// ---------------- kernel 2: flash attention + fused split-k combine --------
// grid (16 qt, 16 bh, 4 ks). Each block emits its l-normalized partial; the
// LAST block per (qt,bh) (split-k counter) re-reads all 4 and writes AOh.
__global__ __launch_bounds__(512) void attn_kernel(
    const unsigned short* __restrict__ Q, const unsigned short* __restrict__ K,
    const unsigned short* __restrict__ Vt, unsigned short* __restrict__ Opart,
    float2* __restrict__ ml, unsigned short* __restrict__ AOh,
    int* __restrict__ ctr) {
  const int qt = blockIdx.x, bh = blockIdx.y, ks = blockIdx.z;
  const int b = bh >> 3, h = bh & 7;
  const int n0 = qt * 128;
  const int tid = threadIdx.x;
  const int w = tid >> 6, lane = tid & 63;
  const int lc = lane & 15, lg = lane >> 4;

  __shared__ __align__(16) unsigned short Ks[2][64][56];  // [buf][key][d +pad]
  __shared__ __align__(16) unsigned short Vs[2][48][68];  // [buf][d][key +pad]

  const unsigned short* Qrow = Q + ((size_t)bh * N_TOK + n0 + 16 * w + lc) * DH;
  const f16x8 qf0 = *(const f16x8*)(Qrow + 8 * lg);
  f16x8 qf1 = {0, 0, 0, 0, 0, 0, 0, 0};
  {
    const f16x4 t = *(const f16x4*)(Qrow + 32 + 4 * lg);
    qf1[0] = t[0]; qf1[1] = t[1]; qf1[2] = t[2]; qf1[3] = t[3];
  }

  const unsigned short* Kg = K + (size_t)bh * N_TOK * DH + (size_t)ks * KEYS_PER_SPLIT * DH;
  const uint* Vg32 = (const uint*)(Vt + (size_t)bh * DH * N_TOK) + ks * (KEYS_PER_SPLIT / 2);

  uint kr[3], vr[3];
  auto issue = [&](int t0) {
    const uint* Ksrc = (const uint*)(Kg + (size_t)t0 * DH);
#pragma unroll
    for (int i = 0; i < 3; ++i) {
      const int dw = tid + i * 512;
      kr[i] = Ksrc[dw];
      vr[i] = Vg32[(size_t)(dw >> 5) * 1024 + (t0 >> 1) + (dw & 31)];
    }
  };
  auto commit = [&](int buf) {
#pragma unroll
    for (int i = 0; i < 3; ++i) {
      const int dw = tid + i * 512;
      const int key = dw / 24, c = dw - key * 24;
      *(uint*)&Ks[buf][key][2 * c] = kr[i];
      *(uint*)&Vs[buf][dw >> 5][2 * (dw & 31)] = vr[i];
    }
  };

  float m_run = -1e30f, l_run = 0.f;
  f32x4 oacc[3] = {{0,0,0,0},{0,0,0,0},{0,0,0,0}};

  issue(0);
  commit(0);

  for (int t = 0; t < KEYS_PER_SPLIT / 64; ++t) {
    const int cur = t & 1;
    if (t < KEYS_PER_SPLIT / 64 - 1) issue((t + 1) * 64);
    __syncthreads();

    f32x4 sac[4];
    __builtin_amdgcn_s_setprio(1);
#pragma unroll
    for (int it = 0; it < 4; ++it) {
      const int krow = 16 * it + lc;
      const f16x8 kf0 = *(const f16x8*)&Ks[cur][krow][8 * lg];
      f16x8 kf1 = {0, 0, 0, 0, 0, 0, 0, 0};
      const f16x4 tt = *(const f16x4*)&Ks[cur][krow][32 + 4 * lg];
      kf1[0] = tt[0]; kf1[1] = tt[1]; kf1[2] = tt[2]; kf1[3] = tt[3];
      const f32x4 z = {0.f, 0.f, 0.f, 0.f};
      f32x4 s = __builtin_amdgcn_mfma_f32_16x16x32_f16(kf0, qf0, z, 0, 0, 0);
      sac[it]  = __builtin_amdgcn_mfma_f32_16x16x32_f16(kf1, qf1, s, 0, 0, 0);
    }
    __builtin_amdgcn_s_setprio(0);

    float mt = -1e30f;
#pragma unroll
    for (int it = 0; it < 4; ++it)
#pragma unroll
      for (int r = 0; r < 4; ++r) mt = fmaxf(mt, sac[it][r]);
    mt = fmaxf(mt, __shfl_xor(mt, 16, 64));
    mt = fmaxf(mt, __shfl_xor(mt, 32, 64));

    if (!__all(mt - m_run <= DEFER_THR)) {
      const float mn = fmaxf(m_run, mt);
      const float rs = exp2g(m_run - mn);
      m_run = mn;
      l_run *= rs;
#pragma unroll
      for (int itd = 0; itd < 3; ++itd)
#pragma unroll
        for (int r = 0; r < 4; ++r) oacc[itd][r] *= rs;
    }

    float p[4][4];
    float ps = 0.f;
#pragma unroll
    for (int it = 0; it < 4; ++it)
#pragma unroll
      for (int r = 0; r < 4; ++r) {
        p[it][r] = exp2g(sac[it][r] - m_run);
        ps += p[it][r];
      }
    ps += __shfl_xor(ps, 16, 64);
    ps += __shfl_xor(ps, 32, 64);
    l_run += ps;

    f16x8 pt[2];
#pragma unroll
    for (int ks2 = 0; ks2 < 2; ++ks2) {
      union { f16x8 v; uint u[4]; } pu;
      pu.u[0] = pk2(p[2 * ks2][0], p[2 * ks2][1]);
      pu.u[1] = pk2(p[2 * ks2][2], p[2 * ks2][3]);
      pu.u[2] = pk2(p[2 * ks2 + 1][0], p[2 * ks2 + 1][1]);
      pu.u[3] = pk2(p[2 * ks2 + 1][2], p[2 * ks2 + 1][3]);
      pt[ks2] = pu.v;
    }

    __builtin_amdgcn_s_setprio(1);
#pragma unroll
    for (int itd = 0; itd < 3; ++itd) {
      const int drow = 16 * itd + lc;
#pragma unroll
      for (int ks2 = 0; ks2 < 2; ++ks2) {
        const f16x4 v0 = *(const f16x4*)&Vs[cur][drow][4 * lg + 32 * ks2];
        const f16x4 v1 = *(const f16x4*)&Vs[cur][drow][4 * lg + 32 * ks2 + 16];
        f16x8 vf;
        vf[0] = v0[0]; vf[1] = v0[1]; vf[2] = v0[2]; vf[3] = v0[3];
        vf[4] = v1[0]; vf[5] = v1[1]; vf[6] = v1[2]; vf[7] = v1[3];
        oacc[itd] = __builtin_amdgcn_mfma_f32_16x16x32_f16(vf, pt[ks2], oacc[itd], 0, 0, 0);
      }
    }
    __builtin_amdgcn_s_setprio(0);

    if (t < KEYS_PER_SPLIT / 64 - 1) commit(cur ^ 1);
  }

  // epilogue: l-NORMALIZED partial (bounded by |V|max, fp16-safe) + (m,l)
  if (lg == 0)
    ml[(size_t)(ks * 16 + bh) * N_TOK + n0 + 16 * w + lc] = make_float2(m_run, l_run);
  const float inv = 1.f / l_run;
  unsigned short* Ap = Opart +
      ((size_t)(ks * B_SZ + b) * N_TOK + n0 + 16 * w + lc) * 384 + h * DH;
#pragma unroll
  for (int itd = 0; itd < 3; ++itd) {
    uint2 pkv;
    pkv.x = pk2(oacc[itd][0] * inv, oacc[itd][1] * inv);
    pkv.y = pk2(oacc[itd][2] * inv, oacc[itd][3] * inv);
    *(uint2*)(Ap + 16 * itd + 4 * lg) = pkv;
  }

  // -------- split-k last-block combine (release/acquire via device fences) --
  __threadfence();            // publish this block's Opart + ml stores
  __syncthreads();            // all threads' fences done before the signal
  __shared__ int lastFlag;
  if (tid == 0) {
    const int prev = atomicAdd(&ctr[qt * 16 + bh], 1);  // device-scope (m20)
    lastFlag = (prev == KSPLIT - 1);
  }
  __syncthreads();
  if (!lastFlag) return;
  __threadfence();            // acquire: see peers' partials

  // per-n combine weights into LDS (K/V buffers are dead now)
  float4* SWc = (float4*)&Ks[0][0][0];   // 128 * 16 B = 2 KB
  if (tid < 128) {
    const int n = n0 + tid;
    const float2 e0 = ml[(size_t)(0 * 16 + bh) * N_TOK + n];
    const float2 e1 = ml[(size_t)(1 * 16 + bh) * N_TOK + n];
    const float2 e2 = ml[(size_t)(2 * 16 + bh) * N_TOK + n];
    const float2 e3 = ml[(size_t)(3 * 16 + bh) * N_TOK + n];
    const float M = fmaxf(fmaxf(e0.x, e1.x), fmaxf(e2.x, e3.x));
    const float g0 = exp2g(e0.x - M) * e0.y, g1 = exp2g(e1.x - M) * e1.y;
    const float g2 = exp2g(e2.x - M) * e2.y, g3 = exp2g(e3.x - M) * e3.y;
    const float ginv = 1.f / (g0 + g1 + g2 + g3);
    SWc[tid] = make_float4(g0 * ginv, g1 * ginv, g2 * ginv, g3 * ginv);
  }
  __syncthreads();

  const size_t PS = (size_t)B_SZ * N_TOK * 384;
  for (int idx = tid; idx < 768; idx += 512) {   // 128 n x 6 vec8-segments
    const int nl = idx / 6, seg = idx - nl * 6;
    const float4 s4 = SWc[nl];
    const size_t o = ((size_t)b * N_TOK + n0 + nl) * 384 + h * DH + seg * 8;
    union U8 { uint4 q; _Float16 e[8]; } u0, u1, u2, u3, r;
    u0.q = *(const uint4*)(Opart + 0 * PS + o);
    u1.q = *(const uint4*)(Opart + 1 * PS + o);
    u2.q = *(const uint4*)(Opart + 2 * PS + o);
    u3.q = *(const uint4*)(Opart + 3 * PS + o);
#pragma unroll
    for (int k = 0; k < 8; k += 2) {
      const float a = (float)u0.e[k] * s4.x + (float)u1.e[k] * s4.y +
                      (float)u2.e[k] * s4.z + (float)u3.e[k] * s4.w;
      const float bb = (float)u0.e[k + 1] * s4.x + (float)u1.e[k + 1] * s4.y +
                       (float)u2.e[k + 1] * s4.z + (float)u3.e[k + 1] * s4.w;
      *(uint*)&r.e[k] = pk2(a, bb);
    }
    *(uint4*)(AOh + o) = r.q;
  }
}

// ---------------- kernel 3: out projection via fp16 MFMA (swapped) ---------
__global__ __launch_bounds__(256) void proj_mfma(
    const unsigned short* __restrict__ AOh, const unsigned short* __restrict__ woh,
    const float* __restrict__ b_out, const float* __restrict__ x,
    float* __restrict__ out) {
  __shared__ __align__(16) unsigned short As[64][72];
  __shared__ __align__(16) unsigned short Bs[128][72];
  const int tid = threadIdx.x;
  const int w = tid >> 6, lane = tid & 63;
  const int lc = lane & 15, lg = lane >> 4;
  const int c0 = blockIdx.x * 64;
  const int m0 = blockIdx.y * 128;
  const int b = m0 >> 11;

  f32x4 acc[4][2];
#pragma unroll
  for (int i = 0; i < 4; ++i)
#pragma unroll
    for (int j = 0; j < 2; ++j) acc[i][j] = (f32x4){0.f, 0.f, 0.f, 0.f};

  const int arow = tid & 63,  aseg = tid >> 6;
  const int brow = tid & 127, bseg = tid >> 7;

  for (int kk = 0; kk < C_IN; kk += 64) {
    {
      const uint4* s = (const uint4*)(woh + (size_t)(c0 + arow) * C_IN + kk + aseg * 16);
      uint4* d = (uint4*)&As[arow][aseg * 16];
      d[0] = s[0]; d[1] = s[1];
      const uint4* s2 = (const uint4*)(AOh + (size_t)(m0 + brow) * C_IN + kk + bseg * 32);
      uint4* d2 = (uint4*)&Bs[brow][bseg * 32];
      d2[0] = s2[0]; d2[1] = s2[1]; d2[2] = s2[2]; d2[3] = s2[3];
    }
    __syncthreads();
    f16x8 a[4][2], bf[2][2];
#pragma unroll
    for (int ct = 0; ct < 4; ++ct)
#pragma unroll
      for (int kh = 0; kh < 2; ++kh)
        a[ct][kh] = *(const f16x8*)&As[16 * ct + lc][32 * kh + 8 * lg];
#pragma unroll
    for (int mt = 0; mt < 2; ++mt)
#pragma unroll
      for (int kh = 0; kh < 2; ++kh)
        bf[mt][kh] = *(const f16x8*)&Bs[32 * w + 16 * mt + lc][32 * kh + 8 * lg];
#pragma unroll
    for (int ct = 0; ct < 4; ++ct)
#pragma unroll
      for (int mt = 0; mt < 2; ++mt)
#pragma unroll
        for (int kh = 0; kh < 2; ++kh)
          acc[ct][mt] = __builtin_amdgcn_mfma_f32_16x16x32_f16(a[ct][kh], bf[mt][kh], acc[ct][mt], 0, 0, 0);
    __syncthreads();
  }

#pragma unroll
  for (int ct = 0; ct < 4; ++ct)
#pragma unroll
    for (int r = 0; r < 4; ++r) {
      const int c = c0 + 16 * ct + 4 * lg + r;
      const float bias = b_out[c];
#pragma unroll
      for (int mt = 0; mt < 2; ++mt) {
        const int n = (m0 + 32 * w + 16 * mt + lc) & 2047;
        const size_t off = ((size_t)b * C_IN + c) * N_TOK + n;
        out[off] = x[off] + bias + acc[ct][mt][r];
      }
    }
}

// ---------------- launch ----------------
extern "C" void kernel_launch(void* const* d_in, const int* in_sizes, int n_in,
                              void* d_out, int out_size, void* d_ws, size_t ws_size,
                              hipStream_t stream) {
  const float* x     = (const float*)d_in[0];
  const float* w_qkv = (const float*)d_in[1];
  const float* w_out = (const float*)d_in[2];
  const float* b_out = (const float*)d_in[3];
  float* out = (float*)d_out;

  char* ws = (char*)d_ws;
  unsigned short* xh    = (unsigned short*)(ws);             //  3,145,728 B
  unsigned short* wqh   = (unsigned short*)(ws + 3145728);   //    884,736 B
  unsigned short* woh   = (unsigned short*)(ws + 4030464);   //    294,912 B
  unsigned short* Qb    = (unsigned short*)(ws + 4325376);   //  3,145,728 B
  unsigned short* Kb    = (unsigned short*)(ws + 7471104);   //  3,145,728 B
  unsigned short* Vb    = (unsigned short*)(ws + 10616832);  //  3,145,728 B
  unsigned short* Opart = (unsigned short*)(ws + 13762560);  // 12,582,912 B (4 parts)
  float2*         mlb   = (float2*)(ws + 26345472);          //  1,048,576 B
  unsigned short* AOh   = (unsigned short*)(ws + 27394048);  //  3,145,728 B
  int*            ctr   = (int*)(ws + 30539776);             //      1,024 B

  tr_kernel<<<dim3(32, 6, 4), 256, 0, stream>>>(x, w_qkv, w_out, xh, wqh, woh, ctr);
  qkv_mfma<<<dim3(32, 18), 256, 0, stream>>>(xh, wqh, Qb, Kb, Vb);
  attn_kernel<<<dim3(16, 16, KSPLIT), 512, 0, stream>>>(Qb, Kb, Vb, Opart, mlb, AOh, ctr);
  proj_mfma<<<dim3(6, 32), 256, 0, stream>>>(AOh, woh, b_out, x, out);
}

// Round 12
// 75.110 us; speedup vs baseline: 4.4893x; 4.4893x over previous
//
#include <hip/hip_runtime.h>

#define B_SZ 2
#define C_IN 384
#define N_TOK 2048
#define HEADS 8
#define DH 48
#define J3 1152
// ATTN_SCALE * log2(e): S is computed in log2 domain (v_exp_f32 is 2^x)
#define QSCALE_LOG2 0.20823509110768f
#define KSPLIT 4
#define KEYS_PER_SPLIT 512               // N_TOK / KSPLIT
#define DEFER_THR 11.0f                  // P bounded by 2^11 = 2048 (fp16-safe)

typedef __attribute__((ext_vector_type(8))) _Float16 f16x8;
typedef __attribute__((ext_vector_type(4))) _Float16 f16x4;
typedef __attribute__((ext_vector_type(4))) float f32x4;

__device__ __forceinline__ unsigned short f2h(float f) {
  _Float16 h = (_Float16)f;
  return __builtin_bit_cast(unsigned short, h);
}
__device__ __forceinline__ uint pk2(float a, float b) {
  return __builtin_bit_cast(uint, __builtin_amdgcn_cvt_pkrtz(a, b));
}
__device__ __forceinline__ float exp2g(float x) {
  return __builtin_amdgcn_exp2f(x);
}

// ---------------- kernel 0: fused transpose+convert prep -------------------
__global__ __launch_bounds__(256) void tr_kernel(
    const float* __restrict__ x, const float* __restrict__ wq,
    const float* __restrict__ wo, unsigned short* __restrict__ xh,
    unsigned short* __restrict__ wqh, unsigned short* __restrict__ woh) {
  const int z = blockIdx.z;
  const float* src;
  unsigned short* dst;
  int C;
  if (z < 2) {
    src = x + (size_t)z * C_IN * N_TOK;
    dst = xh + (size_t)z * N_TOK * C_IN;
    C = N_TOK;
  } else if (z == 2) {
    src = wq; dst = wqh; C = J3;
  } else {
    src = wo; dst = woh; C = C_IN;
  }
  const int c0 = blockIdx.x * 64;
  const int r0 = blockIdx.y * 64;
  if (c0 >= C) return;
  __shared__ unsigned short T[64][74];
  const int tid = threadIdx.x;
  const int cc = tid & 63;
#pragma unroll
  for (int i = 0; i < 16; ++i) {
    const int rr = 4 * i + (tid >> 6);
    T[cc][rr] = f2h(src[(size_t)(r0 + rr) * C + c0 + cc]);
  }
  __syncthreads();
  const int cc2 = tid >> 2;
  const int seg = (tid & 3) * 16;
  uint v[8];
#pragma unroll
  for (int k = 0; k < 8; ++k)
    v[k] = (uint)T[cc2][seg + 2 * k] | ((uint)T[cc2][seg + 2 * k + 1] << 16);
  unsigned short* dp = dst + (size_t)(c0 + cc2) * C_IN + r0 + seg;
  *(uint4*)dp = make_uint4(v[0], v[1], v[2], v[3]);
  *(uint4*)(dp + 8) = make_uint4(v[4], v[5], v[6], v[7]);
}

// ---------------- kernel 1: QKV GEMM via fp16 MFMA -------------------------
// V-blocks (j0 >= 768) transpose their output through LDS so Vo rows store
// n-contiguous (the direct path was a 64-line scatter per store inst).
__global__ __launch_bounds__(256) void qkv_mfma(
    const unsigned short* __restrict__ xh, const unsigned short* __restrict__ wqh,
    unsigned short* __restrict__ Qo, unsigned short* __restrict__ Ko,
    unsigned short* __restrict__ Vo) {
  __shared__ __align__(16) unsigned short Ts[128][72];
  __shared__ __align__(16) unsigned short Ws[64][72];
  const int tid = threadIdx.x;
  const int w = tid >> 6, lane = tid & 63;
  const int lc = lane & 15, lg = lane >> 4;
  const int m0 = blockIdx.x * 128;
  const int j0 = blockIdx.y * 64;
  const int b = m0 >> 11;

  f32x4 acc[2][4];
#pragma unroll
  for (int i = 0; i < 2; ++i)
#pragma unroll
    for (int j = 0; j < 4; ++j) acc[i][j] = (f32x4){0.f, 0.f, 0.f, 0.f};

  const int trow = tid & 127, tseg = tid >> 7;
  const int wrow = tid & 63,  wseg = tid >> 6;

  for (int kk = 0; kk < C_IN; kk += 64) {
    {
      const uint4* s = (const uint4*)(xh + (size_t)(m0 + trow) * C_IN + kk + tseg * 32);
      uint4* d = (uint4*)&Ts[trow][tseg * 32];
      d[0] = s[0]; d[1] = s[1]; d[2] = s[2]; d[3] = s[3];
      const uint4* s2 = (const uint4*)(wqh + (size_t)(j0 + wrow) * C_IN + kk + wseg * 16);
      uint4* d2 = (uint4*)&Ws[wrow][wseg * 16];
      d2[0] = s2[0]; d2[1] = s2[1];
    }
    __syncthreads();
    f16x8 a[2][2], bf[4][2];
#pragma unroll
    for (int mt = 0; mt < 2; ++mt)
#pragma unroll
      for (int kh = 0; kh < 2; ++kh)
        a[mt][kh] = *(const f16x8*)&Ts[32 * w + 16 * mt + lc][32 * kh + 8 * lg];
#pragma unroll
    for (int jt = 0; jt < 4; ++jt)
#pragma unroll
      for (int kh = 0; kh < 2; ++kh)
        bf[jt][kh] = *(const f16x8*)&Ws[16 * jt + lc][32 * kh + 8 * lg];
#pragma unroll
    for (int mt = 0; mt < 2; ++mt)
#pragma unroll
      for (int jt = 0; jt < 4; ++jt)
#pragma unroll
        for (int kh = 0; kh < 2; ++kh)
          acc[mt][jt] = __builtin_amdgcn_mfma_f32_16x16x32_f16(a[mt][kh], bf[jt][kh], acc[mt][jt], 0, 0, 0);
    __syncthreads();
  }

  if (j0 >= 768) {
    // -------- V path: LDS transpose then coalesced row stores --------
    unsigned short* Tv = &Ts[0][0];   // viewed as [64 j][136 m]
#pragma unroll
    for (int jt = 0; jt < 4; ++jt)
#pragma unroll
      for (int mt = 0; mt < 2; ++mt)
#pragma unroll
        for (int r = 0; r < 4; ++r)
          Tv[(16 * jt + lc) * 136 + (32 * w + 16 * mt + 4 * lg + r)] =
              f2h(acc[mt][jt][r]);
    __syncthreads();
    const int n0 = m0 & 2047;
#pragma unroll
    for (int i = 0; i < 4; ++i) {
      const int s = tid + i * 256;
      const int row = s >> 4;
      const int segoff = (s & 15) * 8;
      const int rr2 = j0 - 768 + row;
      const int head = rr2 / DH;
      const int d = rr2 - head * DH;
      const int bh = b * HEADS + head;
      *(uint4*)(Vo + ((size_t)bh * DH + d) * N_TOK + n0 + segoff) =
          *(const uint4*)&Tv[row * 136 + segoff];
    }
  } else {
    // -------- Q/K path: direct stores --------
#pragma unroll
    for (int jt = 0; jt < 4; ++jt) {
      const int jlo = j0 + 16 * jt;
      const int which = jlo / 384;
      const int rr = jlo - which * 384;
      const int head = rr / DH;
      const int dbase = rr - head * DH;
      const int d = dbase + lc;
      const int bh = b * HEADS + head;
#pragma unroll
      for (int mt = 0; mt < 2; ++mt)
#pragma unroll
        for (int r = 0; r < 4; ++r) {
          const int n = (m0 + 32 * w + 16 * mt + 4 * lg + r) & 2047;
          float val = fminf(fmaxf(acc[mt][jt][r], -5.f), 5.f);
          if (which == 0) {
            Qo[((size_t)bh * N_TOK + n) * DH + d] = f2h(val * QSCALE_LOG2);
          } else {
            Ko[((size_t)bh * N_TOK + n) * DH + d] = f2h(val);
          }
        }
    }
  }
}

// ---------------- kernel 2: flash attention, fp16 MFMA, 4-way K-split ------
// log2-domain softmax (scale pre-folded), defer-max (THR=11), l-normalized
// fp16 partials + per-row (m,l).
__global__ __launch_bounds__(512) void attn_kernel(
    const unsigned short* __restrict__ Q, const unsigned short* __restrict__ K,
    const unsigned short* __restrict__ Vt, unsigned short* __restrict__ Opart,
    float2* __restrict__ ml) {
  const int qt = blockIdx.x, bh = blockIdx.y, ks = blockIdx.z;
  const int b = bh >> 3, h = bh & 7;
  const int n0 = qt * 128;
  const int tid = threadIdx.x;
  const int w = tid >> 6, lane = tid & 63;
  const int lc = lane & 15, lg = lane >> 4;

  __shared__ __align__(16) unsigned short Ks[2][64][56];  // [buf][key][d +pad]
  __shared__ __align__(16) unsigned short Vs[2][48][68];  // [buf][d][key +pad]

  const unsigned short* Qrow = Q + ((size_t)bh * N_TOK + n0 + 16 * w + lc) * DH;
  const f16x8 qf0 = *(const f16x8*)(Qrow + 8 * lg);
  f16x8 qf1 = {0, 0, 0, 0, 0, 0, 0, 0};
  {
    const f16x4 t = *(const f16x4*)(Qrow + 32 + 4 * lg);
    qf1[0] = t[0]; qf1[1] = t[1]; qf1[2] = t[2]; qf1[3] = t[3];
  }

  const unsigned short* Kg = K + (size_t)bh * N_TOK * DH + (size_t)ks * KEYS_PER_SPLIT * DH;
  const uint* Vg32 = (const uint*)(Vt + (size_t)bh * DH * N_TOK) + ks * (KEYS_PER_SPLIT / 2);

  uint kr[3], vr[3];
  auto issue = [&](int t0) {
    const uint* Ksrc = (const uint*)(Kg + (size_t)t0 * DH);
#pragma unroll
    for (int i = 0; i < 3; ++i) {
      const int dw = tid + i * 512;
      kr[i] = Ksrc[dw];
      vr[i] = Vg32[(size_t)(dw >> 5) * 1024 + (t0 >> 1) + (dw & 31)];
    }
  };
  auto commit = [&](int buf) {
#pragma unroll
    for (int i = 0; i < 3; ++i) {
      const int dw = tid + i * 512;
      const int key = dw / 24, c = dw - key * 24;
      *(uint*)&Ks[buf][key][2 * c] = kr[i];
      *(uint*)&Vs[buf][dw >> 5][2 * (dw & 31)] = vr[i];
    }
  };

  float m_run = -1e30f, l_run = 0.f;
  f32x4 oacc[3] = {{0,0,0,0},{0,0,0,0},{0,0,0,0}};

  issue(0);
  commit(0);

  for (int t = 0; t < KEYS_PER_SPLIT / 64; ++t) {
    const int cur = t & 1;
    if (t < KEYS_PER_SPLIT / 64 - 1) issue((t + 1) * 64);  // overlap with compute
    __syncthreads();   // commit(cur) from prev iter visible; prev reads done

    f32x4 sac[4];
    __builtin_amdgcn_s_setprio(1);
#pragma unroll
    for (int it = 0; it < 4; ++it) {
      const int krow = 16 * it + lc;
      const f16x8 kf0 = *(const f16x8*)&Ks[cur][krow][8 * lg];
      f16x8 kf1 = {0, 0, 0, 0, 0, 0, 0, 0};
      const f16x4 tt = *(const f16x4*)&Ks[cur][krow][32 + 4 * lg];
      kf1[0] = tt[0]; kf1[1] = tt[1]; kf1[2] = tt[2]; kf1[3] = tt[3];
      const f32x4 z = {0.f, 0.f, 0.f, 0.f};
      f32x4 s = __builtin_amdgcn_mfma_f32_16x16x32_f16(kf0, qf0, z, 0, 0, 0);
      sac[it]  = __builtin_amdgcn_mfma_f32_16x16x32_f16(kf1, qf1, s, 0, 0, 0);
    }
    __builtin_amdgcn_s_setprio(0);

    float mt = -1e30f;
#pragma unroll
    for (int it = 0; it < 4; ++it)
#pragma unroll
      for (int r = 0; r < 4; ++r) mt = fmaxf(mt, sac[it][r]);
    mt = fmaxf(mt, __shfl_xor(mt, 16, 64));
    mt = fmaxf(mt, __shfl_xor(mt, 32, 64));

    // defer-max: skip rescale while row max grows by <= THR (P <= 2^THR)
    if (!__all(mt - m_run <= DEFER_THR)) {
      const float mn = fmaxf(m_run, mt);
      const float rs = exp2g(m_run - mn);   // 0 on first tile
      m_run = mn;
      l_run *= rs;
#pragma unroll
      for (int itd = 0; itd < 3; ++itd)
#pragma unroll
        for (int r = 0; r < 4; ++r) oacc[itd][r] *= rs;
    }

    float p[4][4];
    float ps = 0.f;
#pragma unroll
    for (int it = 0; it < 4; ++it)
#pragma unroll
      for (int r = 0; r < 4; ++r) {
        p[it][r] = exp2g(sac[it][r] - m_run);
        ps += p[it][r];
      }
    ps += __shfl_xor(ps, 16, 64);
    ps += __shfl_xor(ps, 32, 64);
    l_run += ps;

    f16x8 pt[2];
#pragma unroll
    for (int ks2 = 0; ks2 < 2; ++ks2) {
      union { f16x8 v; uint u[4]; } pu;
      pu.u[0] = pk2(p[2 * ks2][0], p[2 * ks2][1]);
      pu.u[1] = pk2(p[2 * ks2][2], p[2 * ks2][3]);
      pu.u[2] = pk2(p[2 * ks2 + 1][0], p[2 * ks2 + 1][1]);
      pu.u[3] = pk2(p[2 * ks2 + 1][2], p[2 * ks2 + 1][3]);
      pt[ks2] = pu.v;
    }

    __builtin_amdgcn_s_setprio(1);
#pragma unroll
    for (int itd = 0; itd < 3; ++itd) {
      const int drow = 16 * itd + lc;
#pragma unroll
      for (int ks2 = 0; ks2 < 2; ++ks2) {
        const f16x4 v0 = *(const f16x4*)&Vs[cur][drow][4 * lg + 32 * ks2];
        const f16x4 v1 = *(const f16x4*)&Vs[cur][drow][4 * lg + 32 * ks2 + 16];
        f16x8 vf;
        vf[0] = v0[0]; vf[1] = v0[1]; vf[2] = v0[2]; vf[3] = v0[3];
        vf[4] = v1[0]; vf[5] = v1[1]; vf[6] = v1[2]; vf[7] = v1[3];
        oacc[itd] = __builtin_amdgcn_mfma_f32_16x16x32_f16(vf, pt[ks2], oacc[itd], 0, 0, 0);
      }
    }
    __builtin_amdgcn_s_setprio(0);

    if (t < KEYS_PER_SPLIT / 64 - 1) commit(cur ^ 1);  // vmcnt wait auto-inserted
  }

  // epilogue: l-NORMALIZED partial (bounded by |V|max, fp16-safe) + (m,l)
  if (lg == 0)
    ml[(size_t)(ks * 16 + bh) * N_TOK + n0 + 16 * w + lc] = make_float2(m_run, l_run);
  const float inv = 1.f / l_run;
  unsigned short* Ap = Opart +
      ((size_t)(ks * B_SZ + b) * N_TOK + n0 + 16 * w + lc) * 384 + h * DH;
#pragma unroll
  for (int itd = 0; itd < 3; ++itd) {
    uint2 pkv;
    pkv.x = pk2(oacc[itd][0] * inv, oacc[itd][1] * inv);
    pkv.y = pk2(oacc[itd][2] * inv, oacc[itd][3] * inv);
    *(uint2*)(Ap + 16 * itd + 4 * lg) = pkv;
  }
}

// ---------------- kernel 2b: combine the 4 key-split partials --------------
// Partials are l-normalized: O = sum_i (w_i*l_i) O_i / sum_i (w_i*l_i).
__global__ __launch_bounds__(256) void combine_kernel(
    const unsigned short* __restrict__ Opart, const float2* __restrict__ ml,
    unsigned short* __restrict__ AOh) {
  const int vid = blockIdx.x * 256 + threadIdx.x;  // 196608 vec8's
  const int c8 = vid % 48;
  const int n  = (vid / 48) & 2047;
  const int b  = vid / (48 * 2048);
  const int c0 = c8 * 8;
  const int h  = c0 / 48;
  const int bh = b * 8 + h;
  const size_t PS = (size_t)B_SZ * N_TOK * 384;
  float2 e0 = ml[(size_t)(0 * 16 + bh) * N_TOK + n];
  float2 e1 = ml[(size_t)(1 * 16 + bh) * N_TOK + n];
  float2 e2 = ml[(size_t)(2 * 16 + bh) * N_TOK + n];
  float2 e3 = ml[(size_t)(3 * 16 + bh) * N_TOK + n];
  const float M = fmaxf(fmaxf(e0.x, e1.x), fmaxf(e2.x, e3.x));
  const float g0 = exp2g(e0.x - M) * e0.y, g1 = exp2g(e1.x - M) * e1.y;
  const float g2 = exp2g(e2.x - M) * e2.y, g3 = exp2g(e3.x - M) * e3.y;
  const float inv = 1.f / (g0 + g1 + g2 + g3);
  const float s0 = g0 * inv, s1 = g1 * inv, s2 = g2 * inv, s3 = g3 * inv;
  const size_t o = ((size_t)b * N_TOK + n) * 384 + c0;
  union U8 { uint4 q; _Float16 e[8]; } u0, u1, u2, u3, r;
  u0.q = *(const uint4*)(Opart + 0 * PS + o);
  u1.q = *(const uint4*)(Opart + 1 * PS + o);
  u2.q = *(const uint4*)(Opart + 2 * PS + o);
  u3.q = *(const uint4*)(Opart + 3 * PS + o);
#pragma unroll
  for (int k = 0; k < 8; k += 2) {
    const float a = (float)u0.e[k] * s0 + (float)u1.e[k] * s1 +
                    (float)u2.e[k] * s2 + (float)u3.e[k] * s3;
    const float bb = (float)u0.e[k + 1] * s0 + (float)u1.e[k + 1] * s1 +
                     (float)u2.e[k + 1] * s2 + (float)u3.e[k + 1] * s3;
    *(uint*)&r.e[k] = pk2(a, bb);
  }
  *(uint4*)(AOh + o) = r.q;
}

// ---------------- kernel 3: out projection via fp16 MFMA (swapped) ---------
__global__ __launch_bounds__(256) void proj_mfma(
    const unsigned short* __restrict__ AOh, const unsigned short* __restrict__ woh,
    const float* __restrict__ b_out, const float* __restrict__ x,
    float* __restrict__ out) {
  __shared__ __align__(16) unsigned short As[64][72];
  __shared__ __align__(16) unsigned short Bs[128][72];
  const int tid = threadIdx.x;
  const int w = tid >> 6, lane = tid & 63;
  const int lc = lane & 15, lg = lane >> 4;
  const int c0 = blockIdx.x * 64;
  const int m0 = blockIdx.y * 128;
  const int b = m0 >> 11;

  f32x4 acc[4][2];
#pragma unroll
  for (int i = 0; i < 4; ++i)
#pragma unroll
    for (int j = 0; j < 2; ++j) acc[i][j] = (f32x4){0.f, 0.f, 0.f, 0.f};

  const int arow = tid & 63,  aseg = tid >> 6;
  const int brow = tid & 127, bseg = tid >> 7;

  for (int kk = 0; kk < C_IN; kk += 64) {
    {
      const uint4* s = (const uint4*)(woh + (size_t)(c0 + arow) * C_IN + kk + aseg * 16);
      uint4* d = (uint4*)&As[arow][aseg * 16];
      d[0] = s[0]; d[1] = s[1];
      const uint4* s2 = (const uint4*)(AOh + (size_t)(m0 + brow) * C_IN + kk + bseg * 32);
      uint4* d2 = (uint4*)&Bs[brow][bseg * 32];
      d2[0] = s2[0]; d2[1] = s2[1]; d2[2] = s2[2]; d2[3] = s2[3];
    }
    __syncthreads();
    f16x8 a[4][2], bf[2][2];
#pragma unroll
    for (int ct = 0; ct < 4; ++ct)
#pragma unroll
      for (int kh = 0; kh < 2; ++kh)
        a[ct][kh] = *(const f16x8*)&As[16 * ct + lc][32 * kh + 8 * lg];
#pragma unroll
    for (int mt = 0; mt < 2; ++mt)
#pragma unroll
      for (int kh = 0; kh < 2; ++kh)
        bf[mt][kh] = *(const f16x8*)&Bs[32 * w + 16 * mt + lc][32 * kh + 8 * lg];
#pragma unroll
    for (int ct = 0; ct < 4; ++ct)
#pragma unroll
      for (int mt = 0; mt < 2; ++mt)
#pragma unroll
        for (int kh = 0; kh < 2; ++kh)
          acc[ct][mt] = __builtin_amdgcn_mfma_f32_16x16x32_f16(a[ct][kh], bf[mt][kh], acc[ct][mt], 0, 0, 0);
    __syncthreads();
  }

#pragma unroll
  for (int ct = 0; ct < 4; ++ct)
#pragma unroll
    for (int r = 0; r < 4; ++r) {
      const int c = c0 + 16 * ct + 4 * lg + r;
      const float bias = b_out[c];
#pragma unroll
      for (int mt = 0; mt < 2; ++mt) {
        const int n = (m0 + 32 * w + 16 * mt + lc) & 2047;
        const size_t off = ((size_t)b * C_IN + c) * N_TOK + n;
        out[off] = x[off] + bias + acc[ct][mt][r];
      }
    }
}

// ---------------- launch ----------------
extern "C" void kernel_launch(void* const* d_in, const int* in_sizes, int n_in,
                              void* d_out, int out_size, void* d_ws, size_t ws_size,
                              hipStream_t stream) {
  const float* x     = (const float*)d_in[0];
  const float* w_qkv = (const float*)d_in[1];
  const float* w_out = (const float*)d_in[2];
  const float* b_out = (const float*)d_in[3];
  float* out = (float*)d_out;

  char* ws = (char*)d_ws;
  unsigned short* xh    = (unsigned short*)(ws);             //  3,145,728 B
  unsigned short* wqh   = (unsigned short*)(ws + 3145728);   //    884,736 B
  unsigned short* woh   = (unsigned short*)(ws + 4030464);   //    294,912 B
  unsigned short* Qb    = (unsigned short*)(ws + 4325376);   //  3,145,728 B
  unsigned short* Kb    = (unsigned short*)(ws + 7471104);   //  3,145,728 B
  unsigned short* Vb    = (unsigned short*)(ws + 10616832);  //  3,145,728 B
  unsigned short* Opart = (unsigned short*)(ws + 13762560);  // 12,582,912 B (4 parts)
  float2*         mlb   = (float2*)(ws + 26345472);          //  1,048,576 B
  unsigned short* AOh   = (unsigned short*)(ws + 27394048);  //  3,145,728 B

  tr_kernel<<<dim3(32, 6, 4), 256, 0, stream>>>(x, w_qkv, w_out, xh, wqh, woh);
  qkv_mfma<<<dim3(32, 18), 256, 0, stream>>>(xh, wqh, Qb, Kb, Vb);
  attn_kernel<<<dim3(16, 16, KSPLIT), 512, 0, stream>>>(Qb, Kb, Vb, Opart, mlb);
  combine_kernel<<<dim3(768), 256, 0, stream>>>(Opart, mlb, AOh);
  proj_mfma<<<dim3(6, 32), 256, 0, stream>>>(AOh, woh, b_out, x, out);
}

// Round 13
// 71.592 us; speedup vs baseline: 4.7099x; 1.0491x over previous
//
#include <hip/hip_runtime.h>

#define B_SZ 2
#define C_IN 384
#define N_TOK 2048
#define HEADS 8
#define DH 48
#define J3 1152
// ATTN_SCALE * log2(e): S is computed in log2 domain (v_exp_f32 is 2^x)
#define QSCALE_LOG2 0.20823509110768f
#define KSPLIT 4
#define KEYS_PER_SPLIT 512               // N_TOK / KSPLIT
#define DEFER_THR 11.0f                  // P bounded by 2^11 = 2048 (fp16-safe)

typedef __attribute__((ext_vector_type(8))) _Float16 f16x8;
typedef __attribute__((ext_vector_type(4))) _Float16 f16x4;
typedef __attribute__((ext_vector_type(4))) float f32x4;

__device__ __forceinline__ unsigned short f2h(float f) {
  _Float16 h = (_Float16)f;           // RNE convert
  return __builtin_bit_cast(unsigned short, h);
}
__device__ __forceinline__ uint pk2(float a, float b) {
  return __builtin_bit_cast(uint, __builtin_amdgcn_cvt_pkrtz(a, b));
}
__device__ __forceinline__ float exp2g(float x) {
  return __builtin_amdgcn_exp2f(x);
}

// ---------------- kernel 1: QKV GEMM, fp16 MFMA, fused transpose-staging ---
// Reads x[b][c][n] and w_qkv[c][j] (both k-major fp32) directly; each chunk
// is bounced through LDS (coalesced load -> convert -> transpose) into the
// same Ts[m][k] / Ws[j][k] tiles as before. MFMA loop & epilogue unchanged.
__global__ __launch_bounds__(256) void qkv_mfma(
    const float* __restrict__ x, const float* __restrict__ wq,
    unsigned short* __restrict__ Qo, unsigned short* __restrict__ Ko,
    unsigned short* __restrict__ Vo) {
  __shared__ __align__(16) unsigned short Ts[128][72];
  __shared__ __align__(16) unsigned short Ws[64][72];
  __shared__ __align__(16) unsigned short Xt[64][132];  // bounce: [c][m], pad 132
  __shared__ __align__(16) unsigned short Wt[64][68];   // bounce: [c][j], pad 68
  const int tid = threadIdx.x;
  const int w = tid >> 6, lane = tid & 63;
  const int lc = lane & 15, lg = lane >> 4;
  const int m0 = blockIdx.x * 128;
  const int j0 = blockIdx.y * 64;
  const int b = m0 >> 11;
  const int n0 = m0 & 2047;

  f32x4 acc[2][4];
#pragma unroll
  for (int i = 0; i < 2; ++i)
#pragma unroll
    for (int j = 0; j < 4; ++j) acc[i][j] = (f32x4){0.f, 0.f, 0.f, 0.f};

  const float* xbase = x + (size_t)b * C_IN * N_TOK + n0;

  for (int kk = 0; kk < C_IN; kk += 64) {
    // ---- stage 1: coalesced fp32 loads -> fp16 -> natural-layout bounce ----
#pragma unroll
    for (int i = 0; i < 8; ++i) {                 // x tile: 64 c x 128 n
      const int f = tid + 256 * i;
      const int c = f >> 5, m4 = (f & 31) * 4;
      const float4 v = *(const float4*)(xbase + (size_t)(kk + c) * N_TOK + m4);
      ushort4 h;
      h.x = f2h(v.x); h.y = f2h(v.y); h.z = f2h(v.z); h.w = f2h(v.w);
      *(ushort4*)&Xt[c][m4] = h;
    }
#pragma unroll
    for (int i = 0; i < 4; ++i) {                 // w tile: 64 c x 64 j
      const int f = tid + 256 * i;
      const int c = f >> 4, j4 = (f & 15) * 4;
      const float4 v = *(const float4*)(wq + (size_t)(kk + c) * J3 + j0 + j4);
      ushort4 h;
      h.x = f2h(v.x); h.y = f2h(v.y); h.z = f2h(v.z); h.w = f2h(v.w);
      *(ushort4*)&Wt[c][j4] = h;
    }
    __syncthreads();

    // ---- stage 2: transpose bounce -> MFMA-ready k-contiguous tiles ----
    {
      const int m = tid >> 1, ks = (tid & 1) * 32;   // Ts rows
      unsigned short tmp[32];
#pragma unroll
      for (int j2 = 0; j2 < 32; ++j2) tmp[j2] = Xt[ks + j2][m];
#pragma unroll
      for (int j2 = 0; j2 < 8; ++j2)
        *(ushort4*)&Ts[m][ks + 4 * j2] =
            make_ushort4(tmp[4 * j2], tmp[4 * j2 + 1], tmp[4 * j2 + 2], tmp[4 * j2 + 3]);
      const int jj = tid >> 2, ks2 = (tid & 3) * 16;  // Ws rows
      unsigned short tw[16];
#pragma unroll
      for (int i2 = 0; i2 < 16; ++i2) tw[i2] = Wt[ks2 + i2][jj];
#pragma unroll
      for (int i2 = 0; i2 < 4; ++i2)
        *(ushort4*)&Ws[jj][ks2 + 4 * i2] =
            make_ushort4(tw[4 * i2], tw[4 * i2 + 1], tw[4 * i2 + 2], tw[4 * i2 + 3]);
    }
    __syncthreads();

    // ---- MFMA (unchanged) ----
    f16x8 a[2][2], bf[4][2];
#pragma unroll
    for (int mt = 0; mt < 2; ++mt)
#pragma unroll
      for (int kh = 0; kh < 2; ++kh)
        a[mt][kh] = *(const f16x8*)&Ts[32 * w + 16 * mt + lc][32 * kh + 8 * lg];
#pragma unroll
    for (int jt = 0; jt < 4; ++jt)
#pragma unroll
      for (int kh = 0; kh < 2; ++kh)
        bf[jt][kh] = *(const f16x8*)&Ws[16 * jt + lc][32 * kh + 8 * lg];
#pragma unroll
    for (int mt = 0; mt < 2; ++mt)
#pragma unroll
      for (int jt = 0; jt < 4; ++jt)
#pragma unroll
        for (int kh = 0; kh < 2; ++kh)
          acc[mt][jt] = __builtin_amdgcn_mfma_f32_16x16x32_f16(a[mt][kh], bf[jt][kh], acc[mt][jt], 0, 0, 0);
    __syncthreads();
  }

  if (j0 >= 768) {
    // -------- V path: LDS transpose then coalesced row stores --------
    unsigned short* Tv = &Ts[0][0];   // viewed as [64 j][136 m]
#pragma unroll
    for (int jt = 0; jt < 4; ++jt)
#pragma unroll
      for (int mt = 0; mt < 2; ++mt)
#pragma unroll
        for (int r = 0; r < 4; ++r)
          Tv[(16 * jt + lc) * 136 + (32 * w + 16 * mt + 4 * lg + r)] =
              f2h(acc[mt][jt][r]);
    __syncthreads();
#pragma unroll
    for (int i = 0; i < 4; ++i) {
      const int s = tid + i * 256;
      const int row = s >> 4;
      const int segoff = (s & 15) * 8;
      const int rr2 = j0 - 768 + row;
      const int head = rr2 / DH;
      const int d = rr2 - head * DH;
      const int bh = b * HEADS + head;
      *(uint4*)(Vo + ((size_t)bh * DH + d) * N_TOK + n0 + segoff) =
          *(const uint4*)&Tv[row * 136 + segoff];
    }
  } else {
    // -------- Q/K path: direct stores --------
#pragma unroll
    for (int jt = 0; jt < 4; ++jt) {
      const int jlo = j0 + 16 * jt;
      const int which = jlo / 384;
      const int rr = jlo - which * 384;
      const int head = rr / DH;
      const int dbase = rr - head * DH;
      const int d = dbase + lc;
      const int bh = b * HEADS + head;
#pragma unroll
      for (int mt = 0; mt < 2; ++mt)
#pragma unroll
        for (int r = 0; r < 4; ++r) {
          const int n = (m0 + 32 * w + 16 * mt + 4 * lg + r) & 2047;
          float val = fminf(fmaxf(acc[mt][jt][r], -5.f), 5.f);
          if (which == 0) {
            Qo[((size_t)bh * N_TOK + n) * DH + d] = f2h(val * QSCALE_LOG2);
          } else {
            Ko[((size_t)bh * N_TOK + n) * DH + d] = f2h(val);
          }
        }
    }
  }
}

// ---------------- kernel 2: flash attention, fp16 MFMA, 4-way K-split ------
// log2-domain softmax (scale pre-folded), defer-max (THR=11), l-normalized
// fp16 partials + per-row (m,l).
__global__ __launch_bounds__(512) void attn_kernel(
    const unsigned short* __restrict__ Q, const unsigned short* __restrict__ K,
    const unsigned short* __restrict__ Vt, unsigned short* __restrict__ Opart,
    float2* __restrict__ ml) {
  const int qt = blockIdx.x, bh = blockIdx.y, ks = blockIdx.z;
  const int b = bh >> 3, h = bh & 7;
  const int n0 = qt * 128;
  const int tid = threadIdx.x;
  const int w = tid >> 6, lane = tid & 63;
  const int lc = lane & 15, lg = lane >> 4;

  __shared__ __align__(16) unsigned short Ks[2][64][56];  // [buf][key][d +pad]
  __shared__ __align__(16) unsigned short Vs[2][48][68];  // [buf][d][key +pad]

  const unsigned short* Qrow = Q + ((size_t)bh * N_TOK + n0 + 16 * w + lc) * DH;
  const f16x8 qf0 = *(const f16x8*)(Qrow + 8 * lg);
  f16x8 qf1 = {0, 0, 0, 0, 0, 0, 0, 0};
  {
    const f16x4 t = *(const f16x4*)(Qrow + 32 + 4 * lg);
    qf1[0] = t[0]; qf1[1] = t[1]; qf1[2] = t[2]; qf1[3] = t[3];
  }

  const unsigned short* Kg = K + (size_t)bh * N_TOK * DH + (size_t)ks * KEYS_PER_SPLIT * DH;
  const uint* Vg32 = (const uint*)(Vt + (size_t)bh * DH * N_TOK) + ks * (KEYS_PER_SPLIT / 2);

  uint kr[3], vr[3];
  auto issue = [&](int t0) {
    const uint* Ksrc = (const uint*)(Kg + (size_t)t0 * DH);
#pragma unroll
    for (int i = 0; i < 3; ++i) {
      const int dw = tid + i * 512;
      kr[i] = Ksrc[dw];
      vr[i] = Vg32[(size_t)(dw >> 5) * 1024 + (t0 >> 1) + (dw & 31)];
    }
  };
  auto commit = [&](int buf) {
#pragma unroll
    for (int i = 0; i < 3; ++i) {
      const int dw = tid + i * 512;
      const int key = dw / 24, c = dw - key * 24;
      *(uint*)&Ks[buf][key][2 * c] = kr[i];
      *(uint*)&Vs[buf][dw >> 5][2 * (dw & 31)] = vr[i];
    }
  };

  float m_run = -1e30f, l_run = 0.f;
  f32x4 oacc[3] = {{0,0,0,0},{0,0,0,0},{0,0,0,0}};

  issue(0);
  commit(0);

  for (int t = 0; t < KEYS_PER_SPLIT / 64; ++t) {
    const int cur = t & 1;
    if (t < KEYS_PER_SPLIT / 64 - 1) issue((t + 1) * 64);  // overlap with compute
    __syncthreads();   // commit(cur) from prev iter visible; prev reads done

    f32x4 sac[4];
    __builtin_amdgcn_s_setprio(1);
#pragma unroll
    for (int it = 0; it < 4; ++it) {
      const int krow = 16 * it + lc;
      const f16x8 kf0 = *(const f16x8*)&Ks[cur][krow][8 * lg];
      f16x8 kf1 = {0, 0, 0, 0, 0, 0, 0, 0};
      const f16x4 tt = *(const f16x4*)&Ks[cur][krow][32 + 4 * lg];
      kf1[0] = tt[0]; kf1[1] = tt[1]; kf1[2] = tt[2]; kf1[3] = tt[3];
      const f32x4 z = {0.f, 0.f, 0.f, 0.f};
      f32x4 s = __builtin_amdgcn_mfma_f32_16x16x32_f16(kf0, qf0, z, 0, 0, 0);
      sac[it]  = __builtin_amdgcn_mfma_f32_16x16x32_f16(kf1, qf1, s, 0, 0, 0);
    }
    __builtin_amdgcn_s_setprio(0);

    float mt = -1e30f;
#pragma unroll
    for (int it = 0; it < 4; ++it)
#pragma unroll
      for (int r = 0; r < 4; ++r) mt = fmaxf(mt, sac[it][r]);
    mt = fmaxf(mt, __shfl_xor(mt, 16, 64));
    mt = fmaxf(mt, __shfl_xor(mt, 32, 64));

    // defer-max: skip rescale while row max grows by <= THR (P <= 2^THR)
    if (!__all(mt - m_run <= DEFER_THR)) {
      const float mn = fmaxf(m_run, mt);
      const float rs = exp2g(m_run - mn);   // 0 on first tile
      m_run = mn;
      l_run *= rs;
#pragma unroll
      for (int itd = 0; itd < 3; ++itd)
#pragma unroll
        for (int r = 0; r < 4; ++r) oacc[itd][r] *= rs;
    }

    float p[4][4];
    float ps = 0.f;
#pragma unroll
    for (int it = 0; it < 4; ++it)
#pragma unroll
      for (int r = 0; r < 4; ++r) {
        p[it][r] = exp2g(sac[it][r] - m_run);
        ps += p[it][r];
      }
    ps += __shfl_xor(ps, 16, 64);
    ps += __shfl_xor(ps, 32, 64);
    l_run += ps;

    f16x8 pt[2];
#pragma unroll
    for (int ks2 = 0; ks2 < 2; ++ks2) {
      union { f16x8 v; uint u[4]; } pu;
      pu.u[0] = pk2(p[2 * ks2][0], p[2 * ks2][1]);
      pu.u[1] = pk2(p[2 * ks2][2], p[2 * ks2][3]);
      pu.u[2] = pk2(p[2 * ks2 + 1][0], p[2 * ks2 + 1][1]);
      pu.u[3] = pk2(p[2 * ks2 + 1][2], p[2 * ks2 + 1][3]);
      pt[ks2] = pu.v;
    }

    __builtin_amdgcn_s_setprio(1);
#pragma unroll
    for (int itd = 0; itd < 3; ++itd) {
      const int drow = 16 * itd + lc;
#pragma unroll
      for (int ks2 = 0; ks2 < 2; ++ks2) {
        const f16x4 v0 = *(const f16x4*)&Vs[cur][drow][4 * lg + 32 * ks2];
        const f16x4 v1 = *(const f16x4*)&Vs[cur][drow][4 * lg + 32 * ks2 + 16];
        f16x8 vf;
        vf[0] = v0[0]; vf[1] = v0[1]; vf[2] = v0[2]; vf[3] = v0[3];
        vf[4] = v1[0]; vf[5] = v1[1]; vf[6] = v1[2]; vf[7] = v1[3];
        oacc[itd] = __builtin_amdgcn_mfma_f32_16x16x32_f16(vf, pt[ks2], oacc[itd], 0, 0, 0);
      }
    }
    __builtin_amdgcn_s_setprio(0);

    if (t < KEYS_PER_SPLIT / 64 - 1) commit(cur ^ 1);  // vmcnt wait auto-inserted
  }

  // epilogue: l-NORMALIZED partial (bounded by |V|max, fp16-safe) + (m,l)
  if (lg == 0)
    ml[(size_t)(ks * 16 + bh) * N_TOK + n0 + 16 * w + lc] = make_float2(m_run, l_run);
  const float inv = 1.f / l_run;
  unsigned short* Ap = Opart +
      ((size_t)(ks * B_SZ + b) * N_TOK + n0 + 16 * w + lc) * 384 + h * DH;
#pragma unroll
  for (int itd = 0; itd < 3; ++itd) {
    uint2 pkv;
    pkv.x = pk2(oacc[itd][0] * inv, oacc[itd][1] * inv);
    pkv.y = pk2(oacc[itd][2] * inv, oacc[itd][3] * inv);
    *(uint2*)(Ap + 16 * itd + 4 * lg) = pkv;
  }
}

// ---------------- kernel 2b: combine the 4 key-split partials --------------
// Partials are l-normalized: O = sum_i (w_i*l_i) O_i / sum_i (w_i*l_i).
__global__ __launch_bounds__(256) void combine_kernel(
    const unsigned short* __restrict__ Opart, const float2* __restrict__ ml,
    unsigned short* __restrict__ AOh) {
  const int vid = blockIdx.x * 256 + threadIdx.x;  // 196608 vec8's
  const int c8 = vid % 48;
  const int n  = (vid / 48) & 2047;
  const int b  = vid / (48 * 2048);
  const int c0 = c8 * 8;
  const int h  = c0 / 48;
  const int bh = b * 8 + h;
  const size_t PS = (size_t)B_SZ * N_TOK * 384;
  float2 e0 = ml[(size_t)(0 * 16 + bh) * N_TOK + n];
  float2 e1 = ml[(size_t)(1 * 16 + bh) * N_TOK + n];
  float2 e2 = ml[(size_t)(2 * 16 + bh) * N_TOK + n];
  float2 e3 = ml[(size_t)(3 * 16 + bh) * N_TOK + n];
  const float M = fmaxf(fmaxf(e0.x, e1.x), fmaxf(e2.x, e3.x));
  const float g0 = exp2g(e0.x - M) * e0.y, g1 = exp2g(e1.x - M) * e1.y;
  const float g2 = exp2g(e2.x - M) * e2.y, g3 = exp2g(e3.x - M) * e3.y;
  const float inv = 1.f / (g0 + g1 + g2 + g3);
  const float s0 = g0 * inv, s1 = g1 * inv, s2 = g2 * inv, s3 = g3 * inv;
  const size_t o = ((size_t)b * N_TOK + n) * 384 + c0;
  union U8 { uint4 q; _Float16 e[8]; } u0, u1, u2, u3, r;
  u0.q = *(const uint4*)(Opart + 0 * PS + o);
  u1.q = *(const uint4*)(Opart + 1 * PS + o);
  u2.q = *(const uint4*)(Opart + 2 * PS + o);
  u3.q = *(const uint4*)(Opart + 3 * PS + o);
#pragma unroll
  for (int k = 0; k < 8; k += 2) {
    const float a = (float)u0.e[k] * s0 + (float)u1.e[k] * s1 +
                    (float)u2.e[k] * s2 + (float)u3.e[k] * s3;
    const float bb = (float)u0.e[k + 1] * s0 + (float)u1.e[k + 1] * s1 +
                     (float)u2.e[k + 1] * s2 + (float)u3.e[k + 1] * s3;
    *(uint*)&r.e[k] = pk2(a, bb);
  }
  *(uint4*)(AOh + o) = r.q;
}

// ---------------- kernel 3: out projection, fp16 MFMA, fused w_out staging -
__global__ __launch_bounds__(256) void proj_mfma(
    const unsigned short* __restrict__ AOh, const float* __restrict__ wo,
    const float* __restrict__ b_out, const float* __restrict__ x,
    float* __restrict__ out) {
  __shared__ __align__(16) unsigned short As[64][72];
  __shared__ __align__(16) unsigned short Bs[128][72];
  __shared__ __align__(16) unsigned short Wt2[64][68];  // bounce: [i][c_out]
  const int tid = threadIdx.x;
  const int w = tid >> 6, lane = tid & 63;
  const int lc = lane & 15, lg = lane >> 4;
  const int c0 = blockIdx.x * 64;
  const int m0 = blockIdx.y * 128;
  const int b = m0 >> 11;

  f32x4 acc[4][2];
#pragma unroll
  for (int i = 0; i < 4; ++i)
#pragma unroll
    for (int j = 0; j < 2; ++j) acc[i][j] = (f32x4){0.f, 0.f, 0.f, 0.f};

  const int brow = tid & 127, bseg = tid >> 7;

  for (int kk = 0; kk < C_IN; kk += 64) {
    // ---- stage 1: w_out fp32 tile -> bounce; Bs direct (AOh is k-contig) ----
#pragma unroll
    for (int i = 0; i < 4; ++i) {
      const int f = tid + 256 * i;
      const int c = f >> 4, c4 = (f & 15) * 4;
      const float4 v = *(const float4*)(wo + (size_t)(kk + c) * C_IN + c0 + c4);
      ushort4 h;
      h.x = f2h(v.x); h.y = f2h(v.y); h.z = f2h(v.z); h.w = f2h(v.w);
      *(ushort4*)&Wt2[c][c4] = h;
    }
    {
      const uint4* s2 = (const uint4*)(AOh + (size_t)(m0 + brow) * C_IN + kk + bseg * 32);
      uint4* d2 = (uint4*)&Bs[brow][bseg * 32];
      d2[0] = s2[0]; d2[1] = s2[1]; d2[2] = s2[2]; d2[3] = s2[3];
    }
    __syncthreads();

    // ---- stage 2: transpose Wt2 -> As[c_out][i] ----
    {
      const int cc = tid >> 2, ks2 = (tid & 3) * 16;
      unsigned short tw[16];
#pragma unroll
      for (int i2 = 0; i2 < 16; ++i2) tw[i2] = Wt2[ks2 + i2][cc];
#pragma unroll
      for (int i2 = 0; i2 < 4; ++i2)
        *(ushort4*)&As[cc][ks2 + 4 * i2] =
            make_ushort4(tw[4 * i2], tw[4 * i2 + 1], tw[4 * i2 + 2], tw[4 * i2 + 3]);
    }
    __syncthreads();

    // ---- MFMA (unchanged) ----
    f16x8 a[4][2], bf[2][2];
#pragma unroll
    for (int ct = 0; ct < 4; ++ct)
#pragma unroll
      for (int kh = 0; kh < 2; ++kh)
        a[ct][kh] = *(const f16x8*)&As[16 * ct + lc][32 * kh + 8 * lg];
#pragma unroll
    for (int mt = 0; mt < 2; ++mt)
#pragma unroll
      for (int kh = 0; kh < 2; ++kh)
        bf[mt][kh] = *(const f16x8*)&Bs[32 * w + 16 * mt + lc][32 * kh + 8 * lg];
#pragma unroll
    for (int ct = 0; ct < 4; ++ct)
#pragma unroll
      for (int mt = 0; mt < 2; ++mt)
#pragma unroll
        for (int kh = 0; kh < 2; ++kh)
          acc[ct][mt] = __builtin_amdgcn_mfma_f32_16x16x32_f16(a[ct][kh], bf[mt][kh], acc[ct][mt], 0, 0, 0);
    __syncthreads();
  }

#pragma unroll
  for (int ct = 0; ct < 4; ++ct)
#pragma unroll
    for (int r = 0; r < 4; ++r) {
      const int c = c0 + 16 * ct + 4 * lg + r;
      const float bias = b_out[c];
#pragma unroll
      for (int mt = 0; mt < 2; ++mt) {
        const int n = (m0 + 32 * w + 16 * mt + lc) & 2047;
        const size_t off = ((size_t)b * C_IN + c) * N_TOK + n;
        out[off] = x[off] + bias + acc[ct][mt][r];
      }
    }
}

// ---------------- launch ----------------
extern "C" void kernel_launch(void* const* d_in, const int* in_sizes, int n_in,
                              void* d_out, int out_size, void* d_ws, size_t ws_size,
                              hipStream_t stream) {
  const float* x     = (const float*)d_in[0];
  const float* w_qkv = (const float*)d_in[1];
  const float* w_out = (const float*)d_in[2];
  const float* b_out = (const float*)d_in[3];
  float* out = (float*)d_out;

  char* ws = (char*)d_ws;
  unsigned short* Qb    = (unsigned short*)(ws);             //  3,145,728 B
  unsigned short* Kb    = (unsigned short*)(ws + 3145728);   //  3,145,728 B
  unsigned short* Vb    = (unsigned short*)(ws + 6291456);   //  3,145,728 B
  unsigned short* Opart = (unsigned short*)(ws + 9437184);   // 12,582,912 B (4 parts)
  float2*         mlb   = (float2*)(ws + 22020096);          //  1,048,576 B
  unsigned short* AOh   = (unsigned short*)(ws + 23068672);  //  3,145,728 B

  qkv_mfma<<<dim3(32, 18), 256, 0, stream>>>(x, w_qkv, Qb, Kb, Vb);
  attn_kernel<<<dim3(16, 16, KSPLIT), 512, 0, stream>>>(Qb, Kb, Vb, Opart, mlb);
  combine_kernel<<<dim3(768), 256, 0, stream>>>(Opart, mlb, AOh);
  proj_mfma<<<dim3(6, 32), 256, 0, stream>>>(AOh, w_out, b_out, x, out);
}